// Round 1
// baseline (1492.498 us; speedup 1.0000x reference)
//
#include <hip/hip_runtime.h>
#include <hip/hip_bf16.h>

#define SEQ    128
#define BATCH  8192
#define TOT    (SEQ*BATCH)        /* 1048576 */
#define STRIDE (BATCH*20)         /* 163840  */
#define T3     (TOT*3)            /* 3145728 */

__device__ __forceinline__ float sigm (float x){ return 1.f/(1.f+__expf(-x)); }
__device__ __forceinline__ float tanhx(float x){ return 2.f/(1.f+__expf(-2.f*x)) - 1.f; }
__device__ __forceinline__ float siluf(float x){ return x/(1.f+__expf(-x)); }

// broadcast lane K's value to all lanes within each 32-lane half (BitMode swizzle: and=0, or=K, xor=0)
template<int K>
__device__ __forceinline__ float bc32(float v){
    return __int_as_float(__builtin_amdgcn_ds_swizzle(__float_as_int(v), (K<<5)));
}

// ---------------------------------------------------------------- kernel 1: preprocess + lin1 + ln1 + lin2 + ln2
__global__ __launch_bounds__(256) void k_pre(
    const float* __restrict__ xlni, const float* __restrict__ imean, const float* __restrict__ istd,
    const float* __restrict__ w1,   const float* __restrict__ b1,    const float* __restrict__ g1,
    const float* __restrict__ w2,   const float* __restrict__ b2,    const float* __restrict__ g2,
    float* __restrict__ x2out, __hip_bfloat162* __restrict__ xnout)
{
    __shared__ float sw1[120], sw2[400], sb1[20], sg1[20], sb2[20], sg2[20], sms[4];
    const int t = threadIdx.x;
    for (int i=t;i<120;i+=256) sw1[i]=w1[i];
    for (int i=t;i<400;i+=256) sw2[i]=w2[i];
    if (t<20){ sb1[t]=b1[t]; sg1[t]=g1[t]; sb2[t]=b2[t]; sg2[t]=g2[t]; }
    if (t<2){ sms[t]=imean[t]; sms[2+t]=istd[t]; }
    __syncthreads();
    const int idx = blockIdx.x*256 + t;
    const float dly = xlni[idx*3+0];
    const float dur = xlni[idx*3+1];
    const float rat = xlni[idx*3+2];
    const float xd = (__logf(1e-5f+dly)-sms[0])/sms[2];
    const float xu = (__logf(fminf(fmaxf(dur,100.f),60000.f))-sms[1])/sms[3];
    int r = (int)fmaxf(rat,1.f)-1; r = r<0?0:(r>3?3:r);
    float a[20];
#pragma unroll
    for (int j=0;j<20;j++){
        float v = sw1[j*6+0]*xd + sw1[j*6+1]*xu + sw1[j*6+2+r] + sb1[j];
        a[j] = siluf(v);
    }
    float m=0.f;
#pragma unroll
    for (int j=0;j<20;j++) m+=a[j];
    m*=0.05f;
    float vv=0.f;
#pragma unroll
    for (int j=0;j<20;j++){ float d=a[j]-m; vv+=d*d; }
    float rs = rsqrtf(vv*0.05f+1e-5f);
    float y[20];
#pragma unroll
    for (int j=0;j<20;j++) y[j]=(a[j]-m)*rs*sg1[j];
    float x2[20];
#pragma unroll
    for (int j=0;j<20;j++){
        float v=sb2[j];
#pragma unroll
        for (int k=0;k<20;k++) v+=sw2[j*20+k]*y[k];
        x2[j]=siluf(v);
    }
    const int base = idx*20;
#pragma unroll
    for (int j=0;j<20;j++) x2out[base+j]=x2[j];
    m=0.f;
#pragma unroll
    for (int j=0;j<20;j++) m+=x2[j];
    m*=0.05f;
    vv=0.f;
#pragma unroll
    for (int j=0;j<20;j++){ float d=x2[j]-m; vv+=d*d; }
    rs=rsqrtf(vv*0.05f+1e-5f);
    const int hb = idx*10;
#pragma unroll
    for (int j=0;j<10;j++){
        __hip_bfloat162 p;
        p.x=__float2bfloat16((x2[2*j  ]-m)*rs*sg2[2*j  ]);
        p.y=__float2bfloat16((x2[2*j+1]-m)*rs*sg2[2*j+1]);
        xnout[hb+j]=p;
    }
}

// ---------------------------------------------------------------- kernel 2: fused double LSTM scan
// One 32-lane half-wave handles 4 batch rows; lane u (<20) owns hidden unit u.
// KST(k): broadcast element k of the 4 source vectors, FMA against weight rows {u,20+u,40+u,60+u}, accumulate stats.
#define KST(k) { \
    const float w0_=Wp[( 0+uc)*20+(k)], w1_=Wp[(20+uc)*20+(k)], \
                w2_=Wp[(40+uc)*20+(k)], w3_=Wp[(60+uc)*20+(k)]; \
    const float v0_=bc32<(k)>(s0), v1_=bc32<(k)>(s1), \
                v2_=bc32<(k)>(s2), v3_=bc32<(k)>(s3); \
    ai0+=v0_*w0_; af0+=v0_*w1_; ag0+=v0_*w2_; ao0+=v0_*w3_; sm0+=v0_; sq0+=v0_*v0_; \
    ai1+=v1_*w0_; af1+=v1_*w1_; ag1+=v1_*w2_; ao1+=v1_*w3_; sm1+=v1_; sq1+=v1_*v1_; \
    ai2+=v2_*w0_; af2+=v2_*w1_; ag2+=v2_*w2_; ao2+=v2_*w3_; sm2+=v2_; sq2+=v2_*v2_; \
    ai3+=v3_*w0_; af3+=v3_*w1_; ag3+=v3_*w2_; ao3+=v3_*w3_; sm3+=v3_; sq3+=v3_*v3_; }
#define DOT20 KST(0) KST(1) KST(2) KST(3) KST(4) KST(5) KST(6) KST(7) KST(8) KST(9) \
              KST(10) KST(11) KST(12) KST(13) KST(14) KST(15) KST(16) KST(17) KST(18) KST(19)

#define GATES1(r) { \
    const float I_=sigm(ai##r), F_=sigm(af##r), G_=tanhx(ag##r), O_=sigm(ao##r); \
    c1_##r = F_*c1_##r + I_*G_; \
    h1_##r = O_*tanhx(c1_##r); \
    x3_##r = x2o##r + h1_##r; }

#define FOLD(r) { \
    const float m_=sm##r*0.05f; \
    float v_=sq##r*0.05f - m_*m_; v_=fmaxf(v_,0.f); \
    const float rs_=rsqrtf(v_+1e-5f); \
    ai##r=B2i+rs_*(ai##r-m_*Wsi); af##r=B2f+rs_*(af##r-m_*Wsf); \
    ag##r=B2g+rs_*(ag##r-m_*Wsg); ao##r=B2o+rs_*(ao##r-m_*Wso); }

#define GATES2(r) { \
    const float I_=sigm(ai##r), F_=sigm(af##r), G_=tanhx(ag##r), O_=sigm(ao##r); \
    c2_##r = F_*c2_##r + I_*G_; \
    h2_##r = O_*tanhx(c2_##r); }

__global__ __launch_bounds__(128) void k_scan(
    const __hip_bfloat16* __restrict__ xn1, float* __restrict__ xio,
    const float* __restrict__ wih1, const float* __restrict__ whh1,
    const float* __restrict__ bih1, const float* __restrict__ bhh1,
    const float* __restrict__ ln3g, const float* __restrict__ ln3b,
    const float* __restrict__ wih2, const float* __restrict__ whh2,
    const float* __restrict__ bih2, const float* __restrict__ bhh2)
{
    __shared__ float sA1[1600], sH1[1600], sA2[1600], sH2[1600];
    __shared__ float sb1[80], sb2[80], sws[80];
    const int t = threadIdx.x;
    for (int i=t;i<1600;i+=128){
        sA1[i]=wih1[i];
        sH1[i]=whh1[i];
        sA2[i]=wih2[i]*ln3g[i%20];   // fold ln3 gamma into input weights
        sH2[i]=whh2[i];
    }
    if (t<80){
        sb1[t]=bih1[t]+bhh1[t];
        float a=bih2[t]+bhh2[t], w=0.f;
        for (int k=0;k<20;k++){
            a+=ln3b[k]*wih2[t*20+k];          // fold ln3 beta into bias
            w+=wih2[t*20+k]*ln3g[k];          // row-sum of scaled weights (mean fixup)
        }
        sb2[t]=a; sws[t]=w;
    }
    __syncthreads();

    const int u=t&31, uc=(u<20)?u:0, grp=t>>5;
    const bool act=(u<20);
    const int row0 = blockIdx.x*16 + grp*4;

    const float B1i=sb1[uc],B1f=sb1[20+uc],B1g=sb1[40+uc],B1o=sb1[60+uc];
    const float B2i=sb2[uc],B2f=sb2[20+uc],B2g=sb2[40+uc],B2o=sb2[60+uc];
    const float Wsi=sws[uc],Wsf=sws[20+uc],Wsg=sws[40+uc],Wso=sws[60+uc];

    const int rb0=(row0+0)*20+uc, rb1=(row0+1)*20+uc, rb2=(row0+2)*20+uc, rb3=(row0+3)*20+uc;
    const int wb0=(row0+0)*20+u,  wb1=(row0+1)*20+u,  wb2=(row0+2)*20+u,  wb3=(row0+3)*20+u;

    float h1_0=0.f,h1_1=0.f,h1_2=0.f,h1_3=0.f, c1_0=0.f,c1_1=0.f,c1_2=0.f,c1_3=0.f;
    float h2_0=0.f,h2_1=0.f,h2_2=0.f,h2_3=0.f, c2_0=0.f,c2_1=0.f,c2_2=0.f,c2_3=0.f;

    // prefetch l=0
    float nxv0=__bfloat162float(xn1[rb0]), nxv1=__bfloat162float(xn1[rb1]);
    float nxv2=__bfloat162float(xn1[rb2]), nxv3=__bfloat162float(xn1[rb3]);
    float nx20=xio[rb0], nx21=xio[rb1], nx22=xio[rb2], nx23=xio[rb3];

#pragma unroll 1
    for (int l=0;l<SEQ;l++){
        const float xv0=nxv0,xv1=nxv1,xv2=nxv2,xv3=nxv3;
        const float x2o0=nx20,x2o1=nx21,x2o2=nx22,x2o3=nx23;
        if (l<SEQ-1){
            const int nb=(l+1)*STRIDE;
            nxv0=__bfloat162float(xn1[nb+rb0]); nxv1=__bfloat162float(xn1[nb+rb1]);
            nxv2=__bfloat162float(xn1[nb+rb2]); nxv3=__bfloat162float(xn1[nb+rb3]);
            nx20=xio[nb+rb0]; nx21=xio[nb+rb1]; nx22=xio[nb+rb2]; nx23=xio[nb+rb3];
        }
        // ---- LSTM1: gates = b1 + xn1.W_ih^T + h1.W_hh^T  (xn1 pre-normalized in k_pre)
        float ai0=B1i,ai1=B1i,ai2=B1i,ai3=B1i;
        float af0=B1f,af1=B1f,af2=B1f,af3=B1f;
        float ag0=B1g,ag1=B1g,ag2=B1g,ag3=B1g;
        float ao0=B1o,ao1=B1o,ao2=B1o,ao3=B1o;
        float sm0=0.f,sm1=0.f,sm2=0.f,sm3=0.f,sq0=0.f,sq1=0.f,sq2=0.f,sq3=0.f;
        { const float* Wp=sA1; const float s0=xv0,s1=xv1,s2=xv2,s3=xv3; DOT20 }
        { const float* Wp=sH1; const float s0=h1_0,s1=h1_1,s2=h1_2,s3=h1_3; DOT20 }
        float x3_0,x3_1,x3_2,x3_3;
        GATES1(0) GATES1(1) GATES1(2) GATES1(3)

        // ---- LSTM2: raw dots over x3, LN folded in afterwards (stats fused into DOT20)
        ai0=0.f;ai1=0.f;ai2=0.f;ai3=0.f; af0=0.f;af1=0.f;af2=0.f;af3=0.f;
        ag0=0.f;ag1=0.f;ag2=0.f;ag3=0.f; ao0=0.f;ao1=0.f;ao2=0.f;ao3=0.f;
        sm0=0.f;sm1=0.f;sm2=0.f;sm3=0.f; sq0=0.f;sq1=0.f;sq2=0.f;sq3=0.f;
        { const float* Wp=sA2; const float s0=x3_0,s1=x3_1,s2=x3_2,s3=x3_3; DOT20 }
        FOLD(0) FOLD(1) FOLD(2) FOLD(3)
        { const float* Wp=sH2; const float s0=h2_0,s1=h2_1,s2=h2_2,s3=h2_3; DOT20 }
        GATES2(0) GATES2(1) GATES2(2) GATES2(3)

        if (act){
            const int b=l*STRIDE;
            xio[b+wb0]=x3_0+h2_0;
            xio[b+wb1]=x3_1+h2_1;
            xio[b+wb2]=x3_2+h2_2;
            xio[b+wb3]=x3_3+h2_3;
        }
    }
}

// ---------------------------------------------------------------- kernel 3: post chain + heads
#define LN20(SRC,GAM,DST) { \
    float m_=0.f; \
    _Pragma("unroll") for (int j_=0;j_<20;j_++) m_+=SRC[j_]; \
    m_*=0.05f; \
    float v_=0.f; \
    _Pragma("unroll") for (int j_=0;j_<20;j_++){ float d_=SRC[j_]-m_; v_+=d_*d_; } \
    const float rs_=rsqrtf(v_*0.05f+1e-5f); \
    _Pragma("unroll") for (int j_=0;j_<20;j_++) DST[j_]=(SRC[j_]-m_)*rs_*GAM[j_]; }

__global__ __launch_bounds__(256) void k_post(
    const float* __restrict__ x4in,
    const float* __restrict__ g4, const float* __restrict__ w3, const float* __restrict__ b3,
    const float* __restrict__ g5, const float* __restrict__ w4, const float* __restrict__ b4,
    const float* __restrict__ g6, const float* __restrict__ w5, const float* __restrict__ b5,
    const float* __restrict__ wfw, const float* __restrict__ wfb,
    const float* __restrict__ sfw, const float* __restrict__ sfb,
    const float* __restrict__ dfw, const float* __restrict__ dfb,
    float* __restrict__ out)
{
    __shared__ float s3[400],s4[400],s5[400];
    __shared__ float sb3v[20],sb4v[20],sb5v[20],sg4v[20],sg5v[20],sg6v[20],shw[180],shb[9];
    const int t=threadIdx.x;
    for (int i=t;i<400;i+=256){ s3[i]=w3[i]; s4[i]=w4[i]; s5[i]=w5[i]; }
    if (t<20){ sb3v[t]=b3[t]; sb4v[t]=b4[t]; sb5v[t]=b5[t]; sg4v[t]=g4[t]; sg5v[t]=g5[t]; sg6v[t]=g6[t]; }
    if (t<60){ shw[t]=wfw[t]; shw[60+t]=sfw[t]; shw[120+t]=dfw[t]; }
    if (t<3){ shb[t]=wfb[t]; shb[3+t]=sfb[t]; shb[6+t]=dfb[t]; }
    __syncthreads();
    const int idx=blockIdx.x*256+t;
    const int base=idx*20;
    float x[20];
#pragma unroll
    for (int j=0;j<20;j++) x[j]=x4in[base+j];
    float tn[20];
    LN20(x,sg4v,tn)
    float h[20];
#pragma unroll
    for (int j=0;j<20;j++){
        float v=sb3v[j];
#pragma unroll
        for (int k=0;k<20;k++) v+=s3[j*20+k]*tn[k];
        h[j]=siluf(v);
    }
    LN20(h,sg5v,tn)
#pragma unroll
    for (int j=0;j<20;j++){
        float v=sb4v[j];
#pragma unroll
        for (int k=0;k<20;k++) v+=s4[j*20+k]*tn[k];
        x[j]+=siluf(v);                 // x = x4 + h2
    }
    LN20(x,sg6v,tn)
    float xf[20];
#pragma unroll
    for (int j=0;j<20;j++){
        float v=sb5v[j];
#pragma unroll
        for (int k=0;k<20;k++) v+=s5[j*20+k]*tn[k];
        xf[j]=siluf(v);
    }
    float lg[9];
#pragma unroll
    for (int hd=0;hd<9;hd++){
        float v=shb[hd];
#pragma unroll
        for (int k=0;k<20;k++) v+=shw[hd*20+k]*xf[k];
        lg[hd]=v;
    }
    const float mx=fmaxf(lg[0],fmaxf(lg[1],lg[2]));
    const float e0=__expf(lg[0]-mx), e1=__expf(lg[1]-mx), e2=__expf(lg[2]-mx);
    const float inv=1.f/(e0+e1+e2);
    const int o3=idx*3;
    out[o3+0]=e0*inv; out[o3+1]=e1*inv; out[o3+2]=e2*inv;
#pragma unroll
    for (int j=0;j<3;j++) out[T3+o3+j]   =__expf(fminf(fmaxf(lg[3+j],-25.f),25.f));
#pragma unroll
    for (int j=0;j<3;j++) out[2*T3+o3+j]=__expf(fminf(fmaxf(lg[6+j],-25.f),25.f));
}

// ---------------------------------------------------------------- launch
extern "C" void kernel_launch(void* const* d_in, const int* in_sizes, int n_in,
                              void* d_out, int out_size, void* d_ws, size_t ws_size,
                              hipStream_t stream)
{
    (void)in_sizes; (void)n_in; (void)out_size; (void)ws_size;
    const float* xlni  = (const float*)d_in[0];
    const float* imean = (const float*)d_in[1];
    const float* istd  = (const float*)d_in[2];
    const float* l1w = (const float*)d_in[3];
    const float* l1b = (const float*)d_in[4];
    const float* g1  = (const float*)d_in[5];
    const float* l2w = (const float*)d_in[6];
    const float* l2b = (const float*)d_in[7];
    const float* g2  = (const float*)d_in[8];
    const float* wih1=(const float*)d_in[9];
    const float* whh1=(const float*)d_in[10];
    const float* bih1=(const float*)d_in[11];
    const float* bhh1=(const float*)d_in[12];
    const float* g3  =(const float*)d_in[13];
    const float* b3n =(const float*)d_in[14];
    const float* wih2=(const float*)d_in[15];
    const float* whh2=(const float*)d_in[16];
    const float* bih2=(const float*)d_in[17];
    const float* bhh2=(const float*)d_in[18];
    const float* g4  =(const float*)d_in[19];
    const float* l3w =(const float*)d_in[20];
    const float* l3b =(const float*)d_in[21];
    const float* g5  =(const float*)d_in[22];
    const float* l4w =(const float*)d_in[23];
    const float* l4b =(const float*)d_in[24];
    const float* g6  =(const float*)d_in[25];
    const float* l5w =(const float*)d_in[26];
    const float* l5b =(const float*)d_in[27];
    const float* wfw =(const float*)d_in[28];
    const float* wfb =(const float*)d_in[29];
    const float* sfw =(const float*)d_in[30];
    const float* sfb =(const float*)d_in[31];
    const float* dfw =(const float*)d_in[32];
    const float* dfb =(const float*)d_in[33];

    float* x2 = (float*)d_ws;                                             // TOT*20 fp32 = 83886080 B (x4 in-place)
    __hip_bfloat16* xn1 = (__hip_bfloat16*)((char*)d_ws + 83886080ull);   // TOT*20 bf16 = 41943040 B

    k_pre <<<TOT/256, 256, 0, stream>>>(xlni, imean, istd, l1w, l1b, g1, l2w, l2b, g2,
                                        x2, (__hip_bfloat162*)xn1);
    k_scan<<<BATCH/16, 128, 0, stream>>>(xn1, x2, wih1, whh1, bih1, bhh1, g3, b3n,
                                         wih2, whh2, bih2, bhh2);
    k_post<<<TOT/256, 256, 0, stream>>>(x2, g4, l3w, l3b, g5, l4w, l4b, g6, l5w, l5b,
                                        wfw, wfb, sfw, sfb, dfw, dfb, (float*)d_out);
}

// Round 2
// 582.404 us; speedup vs baseline: 2.5627x; 2.5627x over previous
//
#include <hip/hip_runtime.h>
#include <hip/hip_fp16.h>

#define SEQ    128
#define BATCH  8192
#define NTL    512               /* n-tiles of 16 */
#define TOT    (SEQ*BATCH)       /* 1048576 */
#define T3     (TOT*3)

typedef __attribute__((ext_vector_type(8))) _Float16 half8;
typedef __attribute__((ext_vector_type(4))) float    f32x4;

union H8 { half8 v; ushort s[8]; uint u[4]; };

__device__ __forceinline__ float sigm (float x){ return 1.f/(1.f+__expf(-x)); }
__device__ __forceinline__ float tanhx(float x){ return 2.f/(1.f+__expf(-2.f*x)) - 1.f; }
__device__ __forceinline__ float siluf(float x){ return x/(1.f+__expf(-x)); }
__device__ __forceinline__ ushort f2h(float x){ _Float16 h=(_Float16)x; return __builtin_bit_cast(ushort,h); }
__device__ __forceinline__ float  h2fl(ushort u){ _Float16 h=__builtin_bit_cast(_Float16,u); return (float)h; }

// ---------------------------------------------------------------- kernel 1: preprocess + lin1 + ln1 + lin2 + ln2
// Emits: xn (=ln2(x2)) as f16 MFMA B-fragments [l][nt][lane]{4 dwords}, with B[k=20][n]=1 bias slot.
//        x2 residual as f16 in C-layout: [l][nt][t][lane] (lane = q*16+col, unit u = 4t+q).
__global__ __launch_bounds__(256) void k_pre(
    const float* __restrict__ xlni, const float* __restrict__ imean, const float* __restrict__ istd,
    const float* __restrict__ w1,   const float* __restrict__ b1,    const float* __restrict__ g1,
    const float* __restrict__ w2,   const float* __restrict__ b2,    const float* __restrict__ g2,
    uint4* __restrict__ xnfrag, ushort* __restrict__ x2h)
{
    __shared__ float sw1[120], sw2[400], sb1[20], sg1[20], sb2[20], sg2[20], sms[4];
    const int t = threadIdx.x;
    for (int i=t;i<120;i+=256) sw1[i]=w1[i];
    for (int i=t;i<400;i+=256) sw2[i]=w2[i];
    if (t<20){ sb1[t]=b1[t]; sg1[t]=g1[t]; sb2[t]=b2[t]; sg2[t]=g2[t]; }
    if (t<2){ sms[t]=imean[t]; sms[2+t]=istd[t]; }
    __syncthreads();
    const int idx = blockIdx.x*256 + t;
    const float dly = xlni[idx*3+0];
    const float dur = xlni[idx*3+1];
    const float rat = xlni[idx*3+2];
    const float xd = (__logf(1e-5f+dly)-sms[0])/sms[2];
    const float xu = (__logf(fminf(fmaxf(dur,100.f),60000.f))-sms[1])/sms[3];
    int r = (int)fmaxf(rat,1.f)-1; r = r<0?0:(r>3?3:r);
    float a[20];
#pragma unroll
    for (int j=0;j<20;j++){
        float v = sw1[j*6+0]*xd + sw1[j*6+1]*xu + sw1[j*6+2+r] + sb1[j];
        a[j] = siluf(v);
    }
    float m=0.f;
#pragma unroll
    for (int j=0;j<20;j++) m+=a[j];
    m*=0.05f;
    float vv=0.f;
#pragma unroll
    for (int j=0;j<20;j++){ float d=a[j]-m; vv+=d*d; }
    float rs = rsqrtf(vv*0.05f+1e-5f);
    float y[20];
#pragma unroll
    for (int j=0;j<20;j++) y[j]=(a[j]-m)*rs*sg1[j];
    float x2[20];
#pragma unroll
    for (int j=0;j<20;j++){
        float v=sb2[j];
#pragma unroll
        for (int k=0;k<20;k++) v+=sw2[j*20+k]*y[k];
        x2[j]=siluf(v);
    }
    // ln2
    m=0.f;
#pragma unroll
    for (int j=0;j<20;j++) m+=x2[j];
    m*=0.05f;
    vv=0.f;
#pragma unroll
    for (int j=0;j<20;j++){ float d=x2[j]-m; vv+=d*d; }
    rs=rsqrtf(vv*0.05f+1e-5f);
    float xnv[20];
#pragma unroll
    for (int j=0;j<20;j++) xnv[j]=(x2[j]-m)*rs*sg2[j];

    const int n = idx & 8191;
    const int col = n & 15;
    const size_t fb = (size_t)(idx >> 4) * 64;      // (l*NTL+nt)*64, uint4 units
#pragma unroll
    for (int q=0;q<4;q++){
        uint w[4];
#pragma unroll
        for (int dd=0;dd<4;dd++){
            const int k0=q*8+2*dd;
            const float v0 = (k0<20)? xnv[k0] : (k0==20?1.f:0.f);
            const float v1 = (k0+1<20)? xnv[k0+1] : 0.f;
            w[dd] = (uint)f2h(v0) | ((uint)f2h(v1)<<16);
        }
        xnfrag[fb + q*16 + col] = make_uint4(w[0],w[1],w[2],w[3]);
    }
    const size_t xb = (size_t)(idx >> 4) * 320;
#pragma unroll
    for (int u=0;u<20;u++)
        x2h[xb + (u>>2)*64 + (u&3)*16 + col] = f2h(x2[u]);
}

// ---------------------------------------------------------------- kernel 2: fused double-LSTM scan, MFMA-based
// 1 wave per block; wave owns one 16-column n-tile for all 128 steps.
// M=80 gate rows interleaved as M=4u+g -> C layout gives lane (q,col) unit u=4t+q, gates in regs 0..3.
__global__ __launch_bounds__(64,1) void k_scan(
    const uint4* __restrict__ xnfrag, ushort* x4h,
    const float* __restrict__ wih1, const float* __restrict__ whh1,
    const float* __restrict__ bih1, const float* __restrict__ bhh1,
    const float* __restrict__ ln3g, const float* __restrict__ ln3b,
    const float* __restrict__ wih2, const float* __restrict__ whh2,
    const float* __restrict__ bih2, const float* __restrict__ bhh2)
{
    __shared__ __align__(16) ushort hb1[512], hb2[512], xb3[512];   // [col][32] f16
    const int lane = threadIdx.x;
    const int col = lane & 15, q = lane >> 4;
    const int nt = blockIdx.x;

    for (int i=lane;i<512;i+=64){ hb1[i]=0; hb2[i]=0; xb3[i]=0; }
    if (lane<16) xb3[lane*32+20] = 0x3C00;   // 1.0h: LSTM2 bias slot

    // ---- stage weights as A-fragments in registers (once)
    half8 Aih1[5], Ahh1[5], Aa2[5], Ahh2[5];
#pragma unroll
    for (int t=0;t<5;t++){
        const int M = t*16 + col, u = M>>2, g = M&3, r = g*20+u;
        H8 a0,a1,a2,a3;
#pragma unroll
        for (int j=0;j<8;j++){
            const int k = q*8+j;
            float vih1=0.f, vhh1=0.f, va2=0.f, vhh2=0.f;
            if (k<20){
                vih1 = wih1[r*20+k];
                vhh1 = whh1[r*20+k];
                va2  = wih2[r*20+k]*ln3g[k];     // fold ln3 gamma
                vhh2 = whh2[r*20+k];
            } else if (k==20){
                vih1 = bih1[r]+bhh1[r];          // bias via K-pad slot
                float b2 = bih2[r]+bhh2[r];
                for (int kk=0;kk<20;kk++) b2 += wih2[r*20+kk]*ln3b[kk];  // fold ln3 beta
                va2 = b2;
            }
            a0.s[j]=f2h(vih1); a1.s[j]=f2h(vhh1); a2.s[j]=f2h(va2); a3.s[j]=f2h(vhh2);
        }
        Aih1[t]=a0.v; Ahh1[t]=a1.v; Aa2[t]=a2.v; Ahh2[t]=a3.v;
    }

    H8 hz; 
#pragma unroll
    for (int j=0;j<8;j++) hz.s[j]=0;
    half8 h1f = hz.v, h2f = hz.v;
    float c1[5]={0,0,0,0,0}, c2[5]={0,0,0,0,0};
    const f32x4 Z = {0.f,0.f,0.f,0.f};

    const uint4*  xf  = xnfrag + (size_t)nt*64  + lane;
    ushort*       x4p = x4h    + (size_t)nt*320 + lane;

    uint4 nxn = xf[0];
    ushort nx2[5];
#pragma unroll
    for (int t=0;t<5;t++) nx2[t] = x4p[t*64];

#pragma unroll 1
    for (int l=0;l<SEQ;l++){
        const half8 xnf = __builtin_bit_cast(half8, nxn);
        float x2r[5];
#pragma unroll
        for (int t=0;t<5;t++) x2r[t] = h2fl(nx2[t]);
        if (l<SEQ-1){
            nxn = xf[(size_t)(l+1)*NTL*64];
#pragma unroll
            for (int t=0;t<5;t++) nx2[t] = x4p[(size_t)(l+1)*NTL*320 + t*64];
        }
        // ---- LSTM1
        f32x4 ac[5];
#pragma unroll
        for (int t=0;t<5;t++){
            ac[t] = __builtin_amdgcn_mfma_f32_16x16x32_f16(Aih1[t], xnf, Z, 0,0,0);
            ac[t] = __builtin_amdgcn_mfma_f32_16x16x32_f16(Ahh1[t], h1f, ac[t], 0,0,0);
        }
        float x3[5], s=0.f, ss=0.f;
#pragma unroll
        for (int t=0;t<5;t++){
            const float gi=sigm(ac[t][0]), gf=sigm(ac[t][1]);
            const float gg=tanhx(ac[t][2]), go=sigm(ac[t][3]);
            c1[t] = gf*c1[t] + gi*gg;
            const float h1v = go*tanhx(c1[t]);
            hb1[col*32 + 4*t + q] = f2h(h1v);
            const float xv = x2r[t] + h1v;
            x3[t]=xv; s+=xv; ss+=xv*xv;
        }
        h1f = *reinterpret_cast<const half8*>(&hb1[col*32 + q*8]);   // for step l+1
        // ---- ln3 (stats over the 20 units = 4 q-lanes x 5 regs)
        s  += __shfl_xor(s,16,64);  s  += __shfl_xor(s,32,64);
        ss += __shfl_xor(ss,16,64); ss += __shfl_xor(ss,32,64);
        const float mn = s*0.05f;
        float var = ss*0.05f - mn*mn; var = fmaxf(var,0.f);
        const float rs = rsqrtf(var+1e-5f);
#pragma unroll
        for (int t=0;t<5;t++)
            xb3[col*32 + 4*t + q] = f2h((x3[t]-mn)*rs);
        const half8 x3f = *reinterpret_cast<const half8*>(&xb3[col*32 + q*8]);
        // ---- LSTM2
#pragma unroll
        for (int t=0;t<5;t++){
            ac[t] = __builtin_amdgcn_mfma_f32_16x16x32_f16(Aa2[t],  x3f, Z, 0,0,0);
            ac[t] = __builtin_amdgcn_mfma_f32_16x16x32_f16(Ahh2[t], h2f, ac[t], 0,0,0);
        }
#pragma unroll
        for (int t=0;t<5;t++){
            const float gi=sigm(ac[t][0]), gf=sigm(ac[t][1]);
            const float gg=tanhx(ac[t][2]), go=sigm(ac[t][3]);
            c2[t] = gf*c2[t] + gi*gg;
            const float h2v = go*tanhx(c2[t]);
            hb2[col*32 + 4*t + q] = f2h(h2v);
            x4p[(size_t)l*NTL*320 + t*64] = f2h(x3[t] + h2v);   // x4, in place over x2
        }
        h2f = *reinterpret_cast<const half8*>(&hb2[col*32 + q*8]);
    }
}

// ---------------------------------------------------------------- kernel 3: post chain + heads
#define LN20(SRC,GAM,DST) { \
    float m_=0.f; \
    _Pragma("unroll") for (int j_=0;j_<20;j_++) m_+=SRC[j_]; \
    m_*=0.05f; \
    float v_=0.f; \
    _Pragma("unroll") for (int j_=0;j_<20;j_++){ float d_=SRC[j_]-m_; v_+=d_*d_; } \
    const float rs_=rsqrtf(v_*0.05f+1e-5f); \
    _Pragma("unroll") for (int j_=0;j_<20;j_++) DST[j_]=(SRC[j_]-m_)*rs_*GAM[j_]; }

__global__ __launch_bounds__(256) void k_post(
    const ushort* __restrict__ x4h,
    const float* __restrict__ g4, const float* __restrict__ w3, const float* __restrict__ b3,
    const float* __restrict__ g5, const float* __restrict__ w4, const float* __restrict__ b4,
    const float* __restrict__ g6, const float* __restrict__ w5, const float* __restrict__ b5,
    const float* __restrict__ wfw, const float* __restrict__ wfb,
    const float* __restrict__ sfw, const float* __restrict__ sfb,
    const float* __restrict__ dfw, const float* __restrict__ dfb,
    float* __restrict__ out)
{
    __shared__ float s3[400],s4[400],s5[400];
    __shared__ float sb3v[20],sb4v[20],sb5v[20],sg4v[20],sg5v[20],sg6v[20],shw[180],shb[9];
    const int t=threadIdx.x;
    for (int i=t;i<400;i+=256){ s3[i]=w3[i]; s4[i]=w4[i]; s5[i]=w5[i]; }
    if (t<20){ sb3v[t]=b3[t]; sb4v[t]=b4[t]; sb5v[t]=b5[t]; sg4v[t]=g4[t]; sg5v[t]=g5[t]; sg6v[t]=g6[t]; }
    if (t<60){ shw[t]=wfw[t]; shw[60+t]=sfw[t]; shw[120+t]=dfw[t]; }
    if (t<3){ shb[t]=wfb[t]; shb[3+t]=sfb[t]; shb[6+t]=dfb[t]; }
    __syncthreads();
    const int idx=blockIdx.x*256+t;
    const int n = idx & 8191, col = n & 15;
    const size_t xb = (size_t)(idx>>4)*320;
    float x[20];
#pragma unroll
    for (int u=0;u<20;u++) x[u]=h2fl(x4h[xb + (u>>2)*64 + (u&3)*16 + col]);
    float tn[20];
    LN20(x,sg4v,tn)
    float h[20];
#pragma unroll
    for (int j=0;j<20;j++){
        float v=sb3v[j];
#pragma unroll
        for (int k=0;k<20;k++) v+=s3[j*20+k]*tn[k];
        h[j]=siluf(v);
    }
    LN20(h,sg5v,tn)
#pragma unroll
    for (int j=0;j<20;j++){
        float v=sb4v[j];
#pragma unroll
        for (int k=0;k<20;k++) v+=s4[j*20+k]*tn[k];
        x[j]+=siluf(v);
    }
    LN20(x,sg6v,tn)
    float xf[20];
#pragma unroll
    for (int j=0;j<20;j++){
        float v=sb5v[j];
#pragma unroll
        for (int k=0;k<20;k++) v+=s5[j*20+k]*tn[k];
        xf[j]=siluf(v);
    }
    float lg[9];
#pragma unroll
    for (int hd=0;hd<9;hd++){
        float v=shb[hd];
#pragma unroll
        for (int k=0;k<20;k++) v+=shw[hd*20+k]*xf[k];
        lg[hd]=v;
    }
    const float mx=fmaxf(lg[0],fmaxf(lg[1],lg[2]));
    const float e0=__expf(lg[0]-mx), e1=__expf(lg[1]-mx), e2=__expf(lg[2]-mx);
    const float inv=1.f/(e0+e1+e2);
    const int o3=idx*3;
    out[o3+0]=e0*inv; out[o3+1]=e1*inv; out[o3+2]=e2*inv;
#pragma unroll
    for (int j=0;j<3;j++) out[T3+o3+j]  =__expf(fminf(fmaxf(lg[3+j],-25.f),25.f));
#pragma unroll
    for (int j=0;j<3;j++) out[2*T3+o3+j]=__expf(fminf(fmaxf(lg[6+j],-25.f),25.f));
}

// ---------------------------------------------------------------- launch
extern "C" void kernel_launch(void* const* d_in, const int* in_sizes, int n_in,
                              void* d_out, int out_size, void* d_ws, size_t ws_size,
                              hipStream_t stream)
{
    (void)in_sizes; (void)n_in; (void)out_size; (void)ws_size;
    const float* xlni  = (const float*)d_in[0];
    const float* imean = (const float*)d_in[1];
    const float* istd  = (const float*)d_in[2];
    const float* l1w = (const float*)d_in[3];
    const float* l1b = (const float*)d_in[4];
    const float* g1  = (const float*)d_in[5];
    const float* l2w = (const float*)d_in[6];
    const float* l2b = (const float*)d_in[7];
    const float* g2  = (const float*)d_in[8];
    const float* wih1=(const float*)d_in[9];
    const float* whh1=(const float*)d_in[10];
    const float* bih1=(const float*)d_in[11];
    const float* bhh1=(const float*)d_in[12];
    const float* g3  =(const float*)d_in[13];
    const float* b3n =(const float*)d_in[14];
    const float* wih2=(const float*)d_in[15];
    const float* whh2=(const float*)d_in[16];
    const float* bih2=(const float*)d_in[17];
    const float* bhh2=(const float*)d_in[18];
    const float* g4  =(const float*)d_in[19];
    const float* l3w =(const float*)d_in[20];
    const float* l3b =(const float*)d_in[21];
    const float* g5  =(const float*)d_in[22];
    const float* l4w =(const float*)d_in[23];
    const float* l4b =(const float*)d_in[24];
    const float* g6  =(const float*)d_in[25];
    const float* l5w =(const float*)d_in[26];
    const float* l5b =(const float*)d_in[27];
    const float* wfw =(const float*)d_in[28];
    const float* wfb =(const float*)d_in[29];
    const float* sfw =(const float*)d_in[30];
    const float* sfb =(const float*)d_in[31];
    const float* dfw =(const float*)d_in[32];
    const float* dfb =(const float*)d_in[33];

    uint4*  xnfrag = (uint4*)d_ws;                                   // 128*512*64*16B = 64 MiB
    ushort* x4h    = (ushort*)((char*)d_ws + 67108864ull);           // TOT*20*2B = 40 MiB (x2 then x4, in place)

    k_pre <<<TOT/256, 256, 0, stream>>>(xlni, imean, istd, l1w, l1b, g1, l2w, l2b, g2,
                                        xnfrag, x4h);
    k_scan<<<NTL, 64, 0, stream>>>(xnfrag, x4h, wih1, whh1, bih1, bhh1, g3, b3n,
                                   wih2, whh2, bih2, bhh2);
    k_post<<<TOT/256, 256, 0, stream>>>(x4h, g4, l3w, l3b, g5, l4w, l4b, g6, l5w, l5b,
                                        wfw, wfb, sfw, sfb, dfw, dfb, (float*)d_out);
}

// Round 3
// 463.277 us; speedup vs baseline: 3.2216x; 1.2571x over previous
//
#include <hip/hip_runtime.h>
#include <hip/hip_fp16.h>

#define SEQ    128
#define BATCH  8192
#define NTL    512               /* n-tiles of 16 */
#define TOT    (SEQ*BATCH)       /* 1048576 */
#define T3     (TOT*3)

typedef __attribute__((ext_vector_type(8))) _Float16 half8;
typedef __attribute__((ext_vector_type(4))) float    f32x4;

union H8 { half8 v; ushort s[8]; uint u[4]; };
union U2S { uint2 u; ushort4 s; };

__device__ __forceinline__ float siluf(float x){ return x/(1.f+__expf(-x)); }
__device__ __forceinline__ ushort f2h(float x){ _Float16 h=(_Float16)x; return __builtin_bit_cast(ushort,h); }
__device__ __forceinline__ float  h2fl(ushort u){ _Float16 h=__builtin_bit_cast(_Float16,u); return (float)h; }
__device__ __forceinline__ uint   pkf(float a, float b){ auto r=__builtin_amdgcn_cvt_pkrtz(a,b); return __builtin_bit_cast(uint,r); }
__device__ __forceinline__ uint   shflx(uint v, int m){ return (uint)__shfl_xor((int)v, m, 64); }

// ---------------------------------------------------------------- kernel 1: preprocess + lin1 + ln1 + lin2 + ln2
__global__ __launch_bounds__(256) void k_pre(
    const float* __restrict__ xlni, const float* __restrict__ imean, const float* __restrict__ istd,
    const float* __restrict__ w1,   const float* __restrict__ b1,    const float* __restrict__ g1,
    const float* __restrict__ w2,   const float* __restrict__ b2,    const float* __restrict__ g2,
    uint4* __restrict__ xnfrag, ushort4* __restrict__ x4a, ushort* __restrict__ x4b)
{
    __shared__ float sw1[120], sw2[400], sb1[20], sg1[20], sb2[20], sg2[20], sms[4];
    const int t = threadIdx.x;
    for (int i=t;i<120;i+=256) sw1[i]=w1[i];
    for (int i=t;i<400;i+=256) sw2[i]=w2[i];
    if (t<20){ sb1[t]=b1[t]; sg1[t]=g1[t]; sb2[t]=b2[t]; sg2[t]=g2[t]; }
    if (t<2){ sms[t]=imean[t]; sms[2+t]=istd[t]; }
    __syncthreads();
    const int idx = blockIdx.x*256 + t;
    const float dly = xlni[idx*3+0];
    const float dur = xlni[idx*3+1];
    const float rat = xlni[idx*3+2];
    const float xd = (__logf(1e-5f+dly)-sms[0])/sms[2];
    const float xu = (__logf(fminf(fmaxf(dur,100.f),60000.f))-sms[1])/sms[3];
    int r = (int)fmaxf(rat,1.f)-1; r = r<0?0:(r>3?3:r);
    float a[20];
#pragma unroll
    for (int j=0;j<20;j++){
        float v = sw1[j*6+0]*xd + sw1[j*6+1]*xu + sw1[j*6+2+r] + sb1[j];
        a[j] = siluf(v);
    }
    float m=0.f;
#pragma unroll
    for (int j=0;j<20;j++) m+=a[j];
    m*=0.05f;
    float vv=0.f;
#pragma unroll
    for (int j=0;j<20;j++){ float d=a[j]-m; vv+=d*d; }
    float rs = rsqrtf(vv*0.05f+1e-5f);
    float y[20];
#pragma unroll
    for (int j=0;j<20;j++) y[j]=(a[j]-m)*rs*sg1[j];
    float x2[20];
#pragma unroll
    for (int j=0;j<20;j++){
        float v=sb2[j];
#pragma unroll
        for (int k=0;k<20;k++) v+=sw2[j*20+k]*y[k];
        x2[j]=siluf(v);
    }
    // ln2
    m=0.f;
#pragma unroll
    for (int j=0;j<20;j++) m+=x2[j];
    m*=0.05f;
    vv=0.f;
#pragma unroll
    for (int j=0;j<20;j++){ float d=x2[j]-m; vv+=d*d; }
    rs=rsqrtf(vv*0.05f+1e-5f);
    float xnv[20];
#pragma unroll
    for (int j=0;j<20;j++) xnv[j]=(x2[j]-m)*rs*sg2[j];

    const int col = idx & 15;
    const size_t fb = (size_t)(idx >> 4) * 64;      // tile base (64 lanes)
#pragma unroll
    for (int qq=0;qq<4;qq++){
        uint w[4];
#pragma unroll
        for (int dd=0;dd<4;dd++){
            const int k0=qq*8+2*dd;
            const float v0 = (k0<20)? xnv[k0] : (k0==20?1.f:0.f);
            const float v1 = (k0+1<20)? xnv[k0+1] : 0.f;
            w[dd] = pkf(v0,v1);
        }
        xnfrag[fb + qq*16 + col] = make_uint4(w[0],w[1],w[2],w[3]);
    }
#pragma unroll
    for (int qq=0;qq<4;qq++){
        ushort4 v;
        v.x=f2h(x2[qq]); v.y=f2h(x2[4+qq]); v.z=f2h(x2[8+qq]); v.w=f2h(x2[12+qq]);
        x4a[fb + qq*16 + col] = v;
        x4b[fb + qq*16 + col] = f2h(x2[16+qq]);
    }
}

// ---------------------------------------------------------------- kernel 2: fused double-LSTM scan
// 1 wave/block, 1 n-tile of 16 cols. All cross-lane transforms via shfl_xor register
// transpose (no LDS). Gate scales (-1/ln2, -2/ln2 for g-row) folded into weights so
// each gate is exp2+add+rcp. Software-pipelined: loop body consumes MFMA results
// issued one iteration earlier.
__global__ __launch_bounds__(64) void k_scan(
    const uint4* __restrict__ xnfrag, ushort4* __restrict__ x4a, ushort* __restrict__ x4b,
    const float* __restrict__ wih1, const float* __restrict__ whh1,
    const float* __restrict__ bih1, const float* __restrict__ bhh1,
    const float* __restrict__ ln3g, const float* __restrict__ ln3b,
    const float* __restrict__ wih2, const float* __restrict__ whh2,
    const float* __restrict__ bih2, const float* __restrict__ bhh2)
{
    const int lane = threadIdx.x & 63;
    const int col = lane & 15, q = lane >> 4;
    const int nt = blockIdx.x;

    // ---- stage scaled weights as A-fragments (once per wave)
    half8 Aih1[5], Ahh1[5], Aa2[5], Ahh2[5];
#pragma unroll
    for (int t=0;t<5;t++){
        const int M = t*16 + col, u = M>>2, g = M&3, r = g*20+u;
        const float sc = (g==2)? -2.885390082f : -1.442695041f;
        H8 a0,a1,a2,a3;
#pragma unroll
        for (int j=0;j<8;j++){
            const int k = q*8+j;
            float vih1=0.f, vhh1=0.f, va2=0.f, vhh2=0.f;
            if (k<20){
                vih1 = wih1[r*20+k]*sc;
                vhh1 = whh1[r*20+k]*sc;
                va2  = wih2[r*20+k]*ln3g[k]*sc;
                vhh2 = whh2[r*20+k]*sc;
            } else if (k==20){
                vih1 = (bih1[r]+bhh1[r])*sc;
                float b2 = bih2[r]+bhh2[r];
                for (int kk=0;kk<20;kk++) b2 += wih2[r*20+kk]*ln3b[kk];
                va2 = b2*sc;
            }
            a0.s[j]=f2h(vih1); a1.s[j]=f2h(vhh1); a2.s[j]=f2h(va2); a3.s[j]=f2h(vhh2);
        }
        Aih1[t]=a0.v; Ahh1[t]=a1.v; Aa2[t]=a2.v; Ahh2[t]=a3.v;
    }

    const bool qb0 = (q&1)!=0, qb1 = (q&2)!=0;
    const float bslot = (q==0)? 1.0f : 0.0f;   // k=20 bias slot (x3 fragment only)

    // C-layout (per-lane 5 units) -> B-fragment: 4x4 lane transpose over q via 2 xor rounds.
    auto XPOSE = [&](float v0,float v1,float v2,float v3,float v4,float vb)->half8{
        uint M0 = pkf(v0,v1), M1 = pkf(v2,v3), M2 = pkf(v4,vb);
        uint t0 = shflx(M1,16), t1 = shflx(M0,16), t3 = shflx(M2,16);
        uint A0 = qb0? t0:M0, A1 = qb0? M1:t1, A2 = qb0? 0u:M2, A3 = qb0? 0u:t3;
        uint s0 = shflx(A2,32), s1 = shflx(A3,32), s2 = shflx(A0,32), s3 = shflx(A1,32);
        uint R0 = qb1? s0:A0, R1 = qb1? s1:A1, R2 = qb1? A2:s2, R3 = qb1? A3:s3;
        H8 o;
        o.u[0]=(R0&0xFFFFu)|(R1<<16);
        o.u[1]=(R2&0xFFFFu)|(R3<<16);
        o.u[2]=(R0>>16)|(R1&0xFFFF0000u);
        o.u[3]=(R2>>16)|(R3&0xFFFF0000u);
        return o.v;
    };
    // gates (weights pre-scaled by -1/ln2; g row by -2/ln2): pure exp2/rcp
    auto GATE = [](const f32x4 a, float& c)->float{
        const float ei=__builtin_amdgcn_exp2f(a[0]);
        const float ef=__builtin_amdgcn_exp2f(a[1]);
        const float eg=__builtin_amdgcn_exp2f(a[2]);
        const float eo=__builtin_amdgcn_exp2f(a[3]);
        const float gi=__builtin_amdgcn_rcpf(1.f+ei);
        const float gf=__builtin_amdgcn_rcpf(1.f+ef);
        const float gg=2.f*__builtin_amdgcn_rcpf(1.f+eg)-1.f;
        const float go=__builtin_amdgcn_rcpf(1.f+eo);
        c = gf*c + gi*gg;
        const float ec=__builtin_amdgcn_exp2f(-2.885390082f*c);
        return go*(2.f*__builtin_amdgcn_rcpf(1.f+ec)-1.f);
    };

    const size_t TSTR = (size_t)NTL*64;  // per-step stride in lane-elements
    const uint4*   xf   = xnfrag + (size_t)nt*64 + lane;
    ushort4*       x4ap = x4a    + (size_t)nt*64 + lane;
    ushort*        x4bp = x4b    + (size_t)nt*64 + lane;

    float c1[5]={0,0,0,0,0}, c2[5]={0,0,0,0,0};
    const f32x4 Z = {0.f,0.f,0.f,0.f};
    f32x4 ac1[5], ac2[5];
    float x3v[5], h1v[5], h2v[5];

    // ================= preamble: step 0 of LSTM1, issue ac2(0), ac1(1) =================
    uint4  xn0 = xf[0];
    ushort4 w0 = x4ap[0]; ushort wb0 = x4bp[0];
#pragma unroll
    for (int t=0;t<5;t++) ac1[t] = __builtin_amdgcn_mfma_f32_16x16x32_f16(Aih1[t], __builtin_bit_cast(half8,xn0), Z, 0,0,0);
    {
        float x2r[5] = { h2fl(w0.x), h2fl(w0.y), h2fl(w0.z), h2fl(w0.w), h2fl(wb0) };
        float s=0.f, ss=0.f;
#pragma unroll
        for (int t=0;t<5;t++){
            const float h = GATE(ac1[t], c1[t]);
            h1v[t]=h;
            const float xv = x2r[t]+h;
            x3v[t]=xv; s+=xv; ss+=xv*xv;
        }
        s  += __shfl_xor(s,16,64);  s  += __shfl_xor(s,32,64);
        ss += __shfl_xor(ss,16,64); ss += __shfl_xor(ss,32,64);
        const float mn = s*0.05f;
        float var = ss*0.05f - mn*mn; var = fmaxf(var,0.f);
        const float rs = __builtin_amdgcn_rsqf(var+1e-5f);
        const float mr = mn*rs;
        half8 x3f = XPOSE(x3v[0]*rs-mr, x3v[1]*rs-mr, x3v[2]*rs-mr, x3v[3]*rs-mr, x3v[4]*rs-mr, bslot);
        half8 h1f = XPOSE(h1v[0],h1v[1],h1v[2],h1v[3],h1v[4], 0.f);
#pragma unroll
        for (int t=0;t<5;t++) ac2[t] = __builtin_amdgcn_mfma_f32_16x16x32_f16(Aa2[t], x3f, Z, 0,0,0);
        uint4 xn1 = xf[TSTR];
#pragma unroll
        for (int t=0;t<5;t++){
            ac1[t] = __builtin_amdgcn_mfma_f32_16x16x32_f16(Aih1[t], __builtin_bit_cast(half8,xn1), Z, 0,0,0);
            ac1[t] = __builtin_amdgcn_mfma_f32_16x16x32_f16(Ahh1[t], h1f, ac1[t], 0,0,0);
        }
    }
    half8 h2f; { H8 z; z.u[0]=0;z.u[1]=0;z.u[2]=0;z.u[3]=0; h2f=z.v; }
    // prefetch slots: xn for steps l+2/l+3; x2 for steps l+1/l+2
    uint4   xnCur = xf[2*TSTR],   xnNxt = xf[3*TSTR];
    ushort4 x2CurA = x4ap[1*TSTR]; ushort x2CurB = x4bp[1*TSTR];
    ushort4 x2NxtA = x4ap[2*TSTR]; ushort x2NxtB = x4bp[2*TSTR];

    // ================= main loop: iter l does gates2(l), gates1(l+1), issues next MFMAs =================
#pragma unroll 1
    for (int l=0;l<127;l++){
        const size_t lpx = (size_t)((l+4<128)? l+4:127) * TSTR;
        const size_t lp2 = (size_t)((l+3<128)? l+3:127) * TSTR;
        uint4   xnNew  = xf[lpx];
        ushort4 x2NewA = x4ap[lp2]; ushort x2NewB = x4bp[lp2];

        // ---- LSTM2 step l
#pragma unroll
        for (int t=0;t<5;t++) h2v[t] = GATE(ac2[t], c2[t]);
        {
            const float o0=x3v[0]+h2v[0], o1=x3v[1]+h2v[1], o2=x3v[2]+h2v[2], o3=x3v[3]+h2v[3], o4=x3v[4]+h2v[4];
            U2S uu; uu.u = make_uint2(pkf(o0,o1), pkf(o2,o3));
            x4ap[(size_t)l*TSTR] = uu.s;
            x4bp[(size_t)l*TSTR] = f2h(o4);
        }
        half8 h2fn = XPOSE(h2v[0],h2v[1],h2v[2],h2v[3],h2v[4], 0.f);

        // ---- LSTM1 step l+1
        float x2r[5] = { h2fl(x2CurA.x), h2fl(x2CurA.y), h2fl(x2CurA.z), h2fl(x2CurA.w), h2fl(x2CurB) };
        float s=0.f, ss=0.f;
#pragma unroll
        for (int t=0;t<5;t++){
            const float h = GATE(ac1[t], c1[t]);
            h1v[t]=h;
            const float xv = x2r[t]+h;
            x3v[t]=xv; s+=xv; ss+=xv*xv;
        }
        s  += __shfl_xor(s,16,64);  s  += __shfl_xor(s,32,64);
        ss += __shfl_xor(ss,16,64); ss += __shfl_xor(ss,32,64);
        const float mn = s*0.05f;
        float var = ss*0.05f - mn*mn; var = fmaxf(var,0.f);
        const float rs = __builtin_amdgcn_rsqf(var+1e-5f);
        const float mr = mn*rs;
        half8 x3f = XPOSE(x3v[0]*rs-mr, x3v[1]*rs-mr, x3v[2]*rs-mr, x3v[3]*rs-mr, x3v[4]*rs-mr, bslot);
        half8 h1f = XPOSE(h1v[0],h1v[1],h1v[2],h1v[3],h1v[4], 0.f);
        h2f = h2fn;

        // ---- issue ac2(l+1), ac1(l+2)
#pragma unroll
        for (int t=0;t<5;t++){
            ac2[t] = __builtin_amdgcn_mfma_f32_16x16x32_f16(Aa2[t],  x3f, Z, 0,0,0);
            ac2[t] = __builtin_amdgcn_mfma_f32_16x16x32_f16(Ahh2[t], h2f, ac2[t], 0,0,0);
        }
        const half8 xnf = __builtin_bit_cast(half8, xnCur);
#pragma unroll
        for (int t=0;t<5;t++){
            ac1[t] = __builtin_amdgcn_mfma_f32_16x16x32_f16(Aih1[t], xnf, Z, 0,0,0);
            ac1[t] = __builtin_amdgcn_mfma_f32_16x16x32_f16(Ahh1[t], h1f, ac1[t], 0,0,0);
        }
        // rotate prefetch slots
        xnCur = xnNxt;  xnNxt = xnNew;
        x2CurA = x2NxtA; x2CurB = x2NxtB;
        x2NxtA = x2NewA; x2NxtB = x2NewB;
    }
    // ================= epilogue: LSTM2 step 127 =================
#pragma unroll
    for (int t=0;t<5;t++) h2v[t] = GATE(ac2[t], c2[t]);
    {
        const float o0=x3v[0]+h2v[0], o1=x3v[1]+h2v[1], o2=x3v[2]+h2v[2], o3=x3v[3]+h2v[3], o4=x3v[4]+h2v[4];
        U2S uu; uu.u = make_uint2(pkf(o0,o1), pkf(o2,o3));
        x4ap[(size_t)127*TSTR] = uu.s;
        x4bp[(size_t)127*TSTR] = f2h(o4);
    }
}

// ---------------------------------------------------------------- kernel 3: post chain + heads
#define LN20(SRC,GAM,DST) { \
    float m_=0.f; \
    _Pragma("unroll") for (int j_=0;j_<20;j_++) m_+=SRC[j_]; \
    m_*=0.05f; \
    float v_=0.f; \
    _Pragma("unroll") for (int j_=0;j_<20;j_++){ float d_=SRC[j_]-m_; v_+=d_*d_; } \
    const float rs_=rsqrtf(v_*0.05f+1e-5f); \
    _Pragma("unroll") for (int j_=0;j_<20;j_++) DST[j_]=(SRC[j_]-m_)*rs_*GAM[j_]; }

__global__ __launch_bounds__(256) void k_post(
    const ushort4* __restrict__ x4a, const ushort* __restrict__ x4b,
    const float* __restrict__ g4, const float* __restrict__ w3, const float* __restrict__ b3,
    const float* __restrict__ g5, const float* __restrict__ w4, const float* __restrict__ b4,
    const float* __restrict__ g6, const float* __restrict__ w5, const float* __restrict__ b5,
    const float* __restrict__ wfw, const float* __restrict__ wfb,
    const float* __restrict__ sfw, const float* __restrict__ sfb,
    const float* __restrict__ dfw, const float* __restrict__ dfb,
    float* __restrict__ out)
{
    __shared__ float s3[400],s4[400],s5[400];
    __shared__ float sb3v[20],sb4v[20],sb5v[20],sg4v[20],sg5v[20],sg6v[20],shw[180],shb[9];
    const int t=threadIdx.x;
    for (int i=t;i<400;i+=256){ s3[i]=w3[i]; s4[i]=w4[i]; s5[i]=w5[i]; }
    if (t<20){ sb3v[t]=b3[t]; sb4v[t]=b4[t]; sb5v[t]=b5[t]; sg4v[t]=g4[t]; sg5v[t]=g5[t]; sg6v[t]=g6[t]; }
    if (t<60){ shw[t]=wfw[t]; shw[60+t]=sfw[t]; shw[120+t]=dfw[t]; }
    if (t<3){ shb[t]=wfb[t]; shb[3+t]=sfb[t]; shb[6+t]=dfb[t]; }
    __syncthreads();
    const int idx=blockIdx.x*256+t;
    const int col = idx&15;
    const size_t cb = (size_t)(idx>>4)*64;
    float x[20];
#pragma unroll
    for (int qq=0;qq<4;qq++){
        const ushort4 va = x4a[cb + qq*16 + col];
        x[qq]=h2fl(va.x); x[4+qq]=h2fl(va.y); x[8+qq]=h2fl(va.z); x[12+qq]=h2fl(va.w);
        x[16+qq]=h2fl(x4b[cb + qq*16 + col]);
    }
    float tn[20];
    LN20(x,sg4v,tn)
    float h[20];
#pragma unroll
    for (int j=0;j<20;j++){
        float v=sb3v[j];
#pragma unroll
        for (int k=0;k<20;k++) v+=s3[j*20+k]*tn[k];
        h[j]=siluf(v);
    }
    LN20(h,sg5v,tn)
#pragma unroll
    for (int j=0;j<20;j++){
        float v=sb4v[j];
#pragma unroll
        for (int k=0;k<20;k++) v+=s4[j*20+k]*tn[k];
        x[j]+=siluf(v);
    }
    LN20(x,sg6v,tn)
    float xf[20];
#pragma unroll
    for (int j=0;j<20;j++){
        float v=sb5v[j];
#pragma unroll
        for (int k=0;k<20;k++) v+=s5[j*20+k]*tn[k];
        xf[j]=siluf(v);
    }
    float lg[9];
#pragma unroll
    for (int hd=0;hd<9;hd++){
        float v=shb[hd];
#pragma unroll
        for (int k=0;k<20;k++) v+=shw[hd*20+k]*xf[k];
        lg[hd]=v;
    }
    const float mx=fmaxf(lg[0],fmaxf(lg[1],lg[2]));
    const float e0=__expf(lg[0]-mx), e1=__expf(lg[1]-mx), e2=__expf(lg[2]-mx);
    const float inv=1.f/(e0+e1+e2);
    const int o3=idx*3;
    out[o3+0]=e0*inv; out[o3+1]=e1*inv; out[o3+2]=e2*inv;
#pragma unroll
    for (int j=0;j<3;j++) out[T3+o3+j]  =__expf(fminf(fmaxf(lg[3+j],-25.f),25.f));
#pragma unroll
    for (int j=0;j<3;j++) out[2*T3+o3+j]=__expf(fminf(fmaxf(lg[6+j],-25.f),25.f));
}

// ---------------------------------------------------------------- launch
extern "C" void kernel_launch(void* const* d_in, const int* in_sizes, int n_in,
                              void* d_out, int out_size, void* d_ws, size_t ws_size,
                              hipStream_t stream)
{
    (void)in_sizes; (void)n_in; (void)out_size; (void)ws_size;
    const float* xlni  = (const float*)d_in[0];
    const float* imean = (const float*)d_in[1];
    const float* istd  = (const float*)d_in[2];
    const float* l1w = (const float*)d_in[3];
    const float* l1b = (const float*)d_in[4];
    const float* g1  = (const float*)d_in[5];
    const float* l2w = (const float*)d_in[6];
    const float* l2b = (const float*)d_in[7];
    const float* g2  = (const float*)d_in[8];
    const float* wih1=(const float*)d_in[9];
    const float* whh1=(const float*)d_in[10];
    const float* bih1=(const float*)d_in[11];
    const float* bhh1=(const float*)d_in[12];
    const float* g3  =(const float*)d_in[13];
    const float* b3n =(const float*)d_in[14];
    const float* wih2=(const float*)d_in[15];
    const float* whh2=(const float*)d_in[16];
    const float* bih2=(const float*)d_in[17];
    const float* bhh2=(const float*)d_in[18];
    const float* g4  =(const float*)d_in[19];
    const float* l3w =(const float*)d_in[20];
    const float* l3b =(const float*)d_in[21];
    const float* g5  =(const float*)d_in[22];
    const float* l4w =(const float*)d_in[23];
    const float* l4b =(const float*)d_in[24];
    const float* g6  =(const float*)d_in[25];
    const float* l5w =(const float*)d_in[26];
    const float* l5b =(const float*)d_in[27];
    const float* wfw =(const float*)d_in[28];
    const float* wfb =(const float*)d_in[29];
    const float* sfw =(const float*)d_in[30];
    const float* sfb =(const float*)d_in[31];
    const float* dfw =(const float*)d_in[32];
    const float* dfb =(const float*)d_in[33];

    uint4*   xnfrag = (uint4*)d_ws;                                   // 64 MiB
    ushort4* x4a    = (ushort4*)((char*)d_ws + 67108864ull);          // 32 MiB (x2 then x4, in place)
    ushort*  x4b    = (ushort*)((char*)d_ws + 100663296ull);          // 8 MiB

    k_pre <<<TOT/256, 256, 0, stream>>>(xlni, imean, istd, l1w, l1b, g1, l2w, l2b, g2,
                                        xnfrag, x4a, x4b);
    k_scan<<<NTL, 64, 0, stream>>>(xnfrag, x4a, x4b, wih1, whh1, bih1, bhh1, g3, b3n,
                                   wih2, whh2, bih2, bhh2);
    k_post<<<TOT/256, 256, 0, stream>>>(x4a, x4b, g4, l3w, l3b, g5, l4w, l4b, g6, l5w, l5b,
                                        wfw, wfb, sfw, sfb, dfw, dfb, (float*)d_out);
}